// Round 16
// baseline (255.682 us; speedup 1.0000x reference)
//
#include <hip/hip_runtime.h>
#include <hip/hip_bf16.h>

typedef unsigned short u16;
typedef unsigned int u32;
typedef __bf16 bf16x8 __attribute__((ext_vector_type(8)));
typedef u16 u16x8 __attribute__((ext_vector_type(8)));
typedef u16 u16x4 __attribute__((ext_vector_type(4)));
typedef float f32x4 __attribute__((ext_vector_type(4)));

__device__ __forceinline__ u16 f2bf(float f) {
  union { float f; unsigned u; } v; v.f = f;
  return (u16)((v.u + 0x7FFFu + ((v.u >> 16) & 1u)) >> 16);
}
__device__ __forceinline__ float bf2f(u16 h) {
  union { unsigned u; float f; } v; v.u = ((unsigned)h) << 16;
  return v.f;
}
__device__ __forceinline__ float asf(u32 u) {
  union { unsigned u; float f; } v; v.u = u; return v.f;
}
struct BfPair { u16 hi, lo; };
__device__ __forceinline__ BfPair split2(float f) {
  BfPair r;
  r.hi = f2bf(f);
  r.lo = f2bf(f - bf2f(r.hi));
  return r;
}
__device__ __forceinline__ bf16x8 as_bf16x8(u16x8 u) {
  union { u16x8 u; bf16x8 b; } v; v.u = u; return v.b;
}
// packed f32->bf16 (RNE): low16 = bf16(a), high16 = bf16(b)
__device__ __forceinline__ u32 cvt_pk(float a, float b) {
  u32 r;
  asm volatile("v_cvt_pk_bf16_f32 %0, %1, %2" : "=v"(r) : "v"(a), "v"(b));
  return r;
}

#define MFMA16(a, b, c) __builtin_amdgcn_mfma_f32_16x16x32_bf16((a), (b), (c), 0, 0, 0)

#define GLD16(gp, lp)                                                          \
  __builtin_amdgcn_global_load_lds(                                            \
      (const __attribute__((address_space(1))) void*)(gp),                     \
      (__attribute__((address_space(3))) void*)(lp), 16, 0, 0)

// ---------------------------------------------------------------------------
// Pre-split: f32 -> bf16 hi/lo planes.
// ---------------------------------------------------------------------------
__global__ __launch_bounds__(256) void split_kernel(
    const float* __restrict__ src, u16* __restrict__ hi, u16* __restrict__ lo, int n4)
{
  int i = blockIdx.x * 256 + threadIdx.x;
  if (i >= n4) return;
  f32x4 v = ((const f32x4*)src)[i];
  u16x4 h, l;
  #pragma unroll
  for (int j = 0; j < 4; j++) { BfPair p = split2(v[j]); h[j] = p.hi; l[j] = p.lo; }
  ((u16x4*)hi)[i] = h;
  ((u16x4*)lo)[i] = l;
}

// ---------------------------------------------------------------------------
// NT GEMM, emulated-fp32 via bf16x3, m97 structure (R12 version — measured).
// ---------------------------------------------------------------------------
template<int OUT_PLANES>
__global__ __launch_bounds__(256, 3) void gemm_nt(
    const u16* __restrict__ Ah, const u16* __restrict__ Al,
    const u16* __restrict__ Bh, const u16* __restrict__ Bl,
    const float* __restrict__ bias,
    void* __restrict__ C0, void* __restrict__ C1,
    int M, int N, int K)
{
  __shared__ u16 Ash[128 * 32], Asl[128 * 32];
  __shared__ u16 Bsh[128 * 32], Bsl[128 * 32];
  const int t = threadIdx.x;
  const int lane = t & 63, w = t >> 6;
  const int l15 = lane & 15, g = lane >> 4;
  const int m0 = blockIdx.x * 128, n0 = blockIdx.y * 128;
  const int lrow = lane >> 2;
  const int lchunk = lane & 3;

  f32x4 acc[4][4] = {};

  for (int k0 = 0; k0 < K; k0 += 32) {
    __syncthreads();
    #pragma unroll
    for (int q = 0; q < 2; q++) {
      const int row = w * 32 + q * 16 + lrow;
      const int sw = lchunk ^ (row & 3) ^ ((row >> 2) & 3);
      const size_t ga = (size_t)(m0 + row) * K + k0 + sw * 8;
      const size_t gb = (size_t)(n0 + row) * K + k0 + sw * 8;
      const int ldsbase = (w * 32 + q * 16) * 32;
      GLD16(Ah + ga, &Ash[ldsbase]);
      GLD16(Al + ga, &Asl[ldsbase]);
      GLD16(Bh + gb, &Bsh[ldsbase]);
      GLD16(Bl + gb, &Bsl[ldsbase]);
    }
    __syncthreads();

    bf16x8 bh[4], bl[4];
    #pragma unroll
    for (int n = 0; n < 4; n++) {
      const int row = (w & 1) * 64 + n * 16 + l15;
      const int slot = g ^ (row & 3) ^ ((row >> 2) & 3);
      const int idx = row * 32 + slot * 8;
      bh[n] = *(const bf16x8*)&Bsh[idx];
      bl[n] = *(const bf16x8*)&Bsl[idx];
    }
    #pragma unroll
    for (int m = 0; m < 4; m++) {
      const int row = (w >> 1) * 64 + m * 16 + l15;
      const int slot = g ^ (row & 3) ^ ((row >> 2) & 3);
      const int idx = row * 32 + slot * 8;
      bf16x8 ah = *(const bf16x8*)&Ash[idx];
      bf16x8 al = *(const bf16x8*)&Asl[idx];
      #pragma unroll
      for (int n = 0; n < 4; n++) {
        acc[m][n] = MFMA16(ah, bh[n], acc[m][n]);
        acc[m][n] = MFMA16(ah, bl[n], acc[m][n]);
        acc[m][n] = MFMA16(al, bh[n], acc[m][n]);
      }
    }
  }

  const int r0 = m0 + (w >> 1) * 64;
  const int c0 = n0 + (w & 1) * 64;
  float bs[4];
  #pragma unroll
  for (int n = 0; n < 4; n++) bs[n] = bias[c0 + n * 16 + l15];
  #pragma unroll
  for (int m = 0; m < 4; m++)
    #pragma unroll
    for (int n = 0; n < 4; n++) {
      const int col = c0 + n * 16 + l15;
      #pragma unroll
      for (int r = 0; r < 4; r++) {
        float v = acc[m][n][r] + bs[n];
        size_t idx = (size_t)(r0 + m * 16 + g * 4 + r) * N + col;
        if (OUT_PLANES) {
          BfPair pp = split2(v);
          ((u16*)C0)[idx] = pp.hi;
          ((u16*)C1)[idx] = pp.lo;
        } else {
          ((float*)C0)[idx] = v;
        }
      }
    }
}

// ---------------------------------------------------------------------------
// Flash attention, KV-split: blockIdx.z selects kt half [0,16) or [16,32).
// Fixed-max softmax makes partials exactly additive: block writes
// UNNORMALIZED f32 O-partial + l-partial; combine kernel finishes.
// R15 numerics otherwise (K hi-only, P hi-only, V hi+lo).
// 2 blocks/CU co-resident -> latency chains of the two halves overlap.
// ---------------------------------------------------------------------------
__global__ __launch_bounds__(512, 2) void attn_kernel(
    const u16* __restrict__ qkv_h, const u16* __restrict__ qkv_l,
    float* __restrict__ O0, float* __restrict__ O1,
    float* __restrict__ l0, float* __restrict__ l1)
{
  const int bh = blockIdx.x;              // b*8 + h
  const int b = bh >> 3, h = bh & 7;
  const int q0 = blockIdx.y * 256;
  const int kt0 = blockIdx.z * 16;
  const int t = threadIdx.x, lane = t & 63, w = t >> 6;
  const int l15 = lane & 15, g = lane >> 4;
  const int wh = w >> 2, wl = w & 3;

  __shared__ u16 Ksh[64 * 72];
  __shared__ u16 Vsh[64 * 72], Vsl[64 * 72];   // V^T, key-swizzled
  __shared__ u16 Ps[8][32 * 72];               // per-wave P (hi only)

  const size_t rowbase = (size_t)b * 2048;
  const float QSC = 0.125f * 1.44269504088896f;  // fold 1/sqrt(64) and log2(e)

  bf16x8 qbh[2][2], qbl[2][2];
  #pragma unroll
  for (int i = 0; i < 2; i++) {
    size_t qoff = (rowbase + q0 + wh * 128 + i * 64 + wl * 16 + l15) * 1536 + h * 64 + g * 8;
    #pragma unroll
    for (int kc = 0; kc < 2; kc++) {
      u16x8 uh = *(const u16x8*)(qkv_h + qoff + kc * 32);
      u16x8 ul = *(const u16x8*)(qkv_l + qoff + kc * 32);
      #pragma unroll
      for (int j = 0; j < 8; j++) {
        float v = (bf2f(uh[j]) + bf2f(ul[j])) * QSC;
        BfPair p = split2(v);
        uh[j] = p.hi; ul[j] = p.lo;
      }
      qbh[i][kc] = as_bf16x8(uh);
      qbl[i][kc] = as_bf16x8(ul);
    }
  }

  f32x4 oacc[2][4] = {};
  float l_q[2] = {0.f, 0.f};

  const int srow = t >> 3, scol = (t & 7) * 8;
  u16x8 skh, svh, svl;
  {
    size_t off = (rowbase + kt0 * 64 + srow) * 1536 + h * 64 + scol;
    skh = *(const u16x8*)(qkv_h + off + 512);
    svh = *(const u16x8*)(qkv_h + off + 1024);
    svl = *(const u16x8*)(qkv_l + off + 1024);
  }

  for (int kt = kt0; kt < kt0 + 16; kt++) {
    __syncthreads();
    {
      *(u16x8*)&Ksh[srow * 72 + scol] = skh;
      int rk = (srow + scol) & 63;               // key-swizzle
      #pragma unroll
      for (int j = 0; j < 8; j++) {
        Vsh[(scol + j) * 72 + rk] = svh[j];
        Vsl[(scol + j) * 72 + rk] = svl[j];
      }
    }
    if (kt + 1 < kt0 + 16) {
      size_t off = (rowbase + (kt + 1) * 64 + srow) * 1536 + h * 64 + scol;
      skh = *(const u16x8*)(qkv_h + off + 512);
      svh = *(const u16x8*)(qkv_h + off + 1024);
      svl = *(const u16x8*)(qkv_l + off + 1024);
    }
    __syncthreads();

    f32x4 sa0[4] = {}, sa1[4] = {};
    #pragma unroll
    for (int kc = 0; kc < 2; kc++) {
      #pragma unroll
      for (int cb = 0; cb < 4; cb++) {
        int ki = (cb * 16 + l15) * 72 + g * 8 + kc * 32;
        bf16x8 kh = *(const bf16x8*)&Ksh[ki];
        sa0[cb] = MFMA16(kh, qbh[0][kc], sa0[cb]);
        sa1[cb] = MFMA16(kh, qbh[1][kc], sa1[cb]);
        sa0[cb] = MFMA16(kh, qbl[0][kc], sa0[cb]);
        sa1[cb] = MFMA16(kh, qbl[1][kc], sa1[cb]);
      }
    }

    // fixed-max softmax: p = exp2(s'); pack hi words only
    u32 hw[2][4][2];
    #pragma unroll
    for (int i = 0; i < 2; i++) {
      f32x4* sa = (i == 0) ? sa0 : sa1;
      float rs = 0.f;
      #pragma unroll
      for (int cb = 0; cb < 4; cb++) {
        #pragma unroll
        for (int r = 0; r < 4; r++) {
          float p = exp2f(sa[cb][r]);
          sa[cb][r] = p;
          rs += p;
        }
        hw[i][cb][0] = cvt_pk(sa[cb][0], sa[cb][1]);
        hw[i][cb][1] = cvt_pk(sa[cb][2], sa[cb][3]);
      }
      rs += __shfl_xor(rs, 16, 64);
      rs += __shfl_xor(rs, 32, 64);
      l_q[i] += rs;
    }

    // P hi plane: write, read A-frags (single roundtrip)
    #pragma unroll
    for (int i = 0; i < 2; i++)
      #pragma unroll
      for (int cb = 0; cb < 4; cb++) {
        u32* dst = (u32*)&Ps[w][(i * 16 + l15) * 72 + cb * 16 + g * 4];
        dst[0] = hw[i][cb][0]; dst[1] = hw[i][cb][1];
      }
    asm volatile("s_waitcnt lgkmcnt(0)" ::: "memory");
    __builtin_amdgcn_sched_barrier(0);
    bf16x8 pah[2][2];
    #pragma unroll
    for (int i = 0; i < 2; i++)
      #pragma unroll
      for (int kc = 0; kc < 2; kc++)
        pah[i][kc] = *(const bf16x8*)&Ps[w][(i * 16 + l15) * 72 + kc * 32 + g * 8];

    // PV for both tiles: pah * (vbh + vbl)
    #pragma unroll
    for (int kc = 0; kc < 2; kc++) {
      #pragma unroll
      for (int cb = 0; cb < 4; cb++) {
        int d = cb * 16 + l15;
        int rk0 = (g * 8 + kc * 32 + (d & 56)) & 63;
        bf16x8 vbh = *(const bf16x8*)&Vsh[d * 72 + rk0];
        bf16x8 vbl = *(const bf16x8*)&Vsl[d * 72 + rk0];
        oacc[0][cb] = MFMA16(pah[0][kc], vbh, oacc[0][cb]);
        oacc[1][cb] = MFMA16(pah[1][kc], vbh, oacc[1][cb]);
        oacc[0][cb] = MFMA16(pah[0][kc], vbl, oacc[0][cb]);
        oacc[1][cb] = MFMA16(pah[1][kc], vbl, oacc[1][cb]);
      }
    }
  }

  // epilogue: write UNNORMALIZED f32 O-partial + l-partial for this kt-half
  float* Op = (blockIdx.z == 0) ? O0 : O1;
  float* lp = (blockIdx.z == 0) ? l0 : l1;
  if (g == 0) {
    #pragma unroll
    for (int i = 0; i < 2; i++) {
      int qrow = q0 + wh * 128 + i * 64 + wl * 16 + l15;
      lp[(size_t)bh * 2048 + qrow] = l_q[i];
    }
  }
  #pragma unroll
  for (int i = 0; i < 2; i++)
    #pragma unroll
    for (int r = 0; r < 4; r++) {
      int row = q0 + wh * 128 + i * 64 + wl * 16 + g * 4 + r;
      size_t base = (rowbase + row) * 512 + h * 64;
      #pragma unroll
      for (int cb = 0; cb < 4; cb++)
        Op[base + cb * 16 + l15] = oacc[i][cb][r];
    }
}

// ---------------------------------------------------------------------------
// Combine: ctx = split((O0+O1)/(l0+l1)). Memory-bound, ~50 MB.
// ---------------------------------------------------------------------------
__global__ __launch_bounds__(256) void combine_kernel(
    const float* __restrict__ O0, const float* __restrict__ O1,
    const float* __restrict__ l0, const float* __restrict__ l1,
    u16* __restrict__ ch, u16* __restrict__ cl)
{
  int i = blockIdx.x * 256 + threadIdx.x;   // f32x4 units over 8192*512
  if (i >= 1048576) return;
  f32x4 a = ((const f32x4*)O0)[i];
  f32x4 c = ((const f32x4*)O1)[i];
  int elem = i * 4;
  int row = elem >> 9;            // global row (b*2048 + q)
  int d = elem & 511;
  int bb = row >> 11, q = row & 2047, h = d >> 6;
  size_t li = ((size_t)(bb * 8 + h)) * 2048 + q;
  float inv = 1.0f / (l0[li] + l1[li]);
  u16x4 hh, ll;
  #pragma unroll
  for (int j = 0; j < 4; j++) {
    BfPair p = split2((a[j] + c[j]) * inv);
    hh[j] = p.hi; ll[j] = p.lo;
  }
  ((u16x4*)ch)[i] = hh;
  ((u16x4*)cl)[i] = ll;
}

// ---------------------------------------------------------------------------
// aff + per-32-row partial sum/max over s (unchanged, measured fast).
// ---------------------------------------------------------------------------
__global__ __launch_bounds__(256) void aff_reduce(
    const float* __restrict__ att, const float* __restrict__ cw,
    const float* __restrict__ cbias, float* __restrict__ psum, float* __restrict__ pmax)
{
  const int b = blockIdx.x, sb = blockIdx.y;
  const int t = threadIdx.x;
  const int n = t & 63, rg = t >> 6;
  __shared__ float cws[64 * 65];
  __shared__ float ats[32 * 65];
  __shared__ float reds[256], redm[256];

  float acc[8] = {};
  for (int kc = 0; kc < 8; kc++) {
    __syncthreads();
    #pragma unroll
    for (int i = 0; i < 4; i++) {
      int c = t + i * 256;
      int row = c >> 4, col = (c & 15) * 4;
      f32x4 v = *(const f32x4*)(cw + (size_t)row * 512 + kc * 64 + col);
      cws[row * 65 + col + 0] = v[0]; cws[row * 65 + col + 1] = v[1];
      cws[row * 65 + col + 2] = v[2]; cws[row * 65 + col + 3] = v[3];
    }
    #pragma unroll
    for (int i = 0; i < 2; i++) {
      int c = t + i * 256;
      int row = c >> 4, col = (c & 15) * 4;
      f32x4 v = *(const f32x4*)(att + ((size_t)b * 2048 + sb * 32 + row) * 512 + kc * 64 + col);
      ats[row * 65 + col + 0] = v[0]; ats[row * 65 + col + 1] = v[1];
      ats[row * 65 + col + 2] = v[2]; ats[row * 65 + col + 3] = v[3];
    }
    __syncthreads();
    for (int k = 0; k < 64; k++) {
      float c = cws[n * 65 + k];
      #pragma unroll
      for (int r = 0; r < 8; r++)
        acc[r] += ats[(rg * 8 + r) * 65 + k] * c;
    }
  }
  const float bn = cbias[n];
  float s = 0.f, m = -1e30f;
  #pragma unroll
  for (int r = 0; r < 8; r++) {
    float v = acc[r] + bn;
    s += v; m = fmaxf(m, v);
  }
  reds[t] = s; redm[t] = m;
  __syncthreads();
  if (t < 64) {
    float ss = reds[t] + reds[64 + t] + reds[128 + t] + reds[192 + t];
    float mm = fmaxf(fmaxf(redm[t], redm[64 + t]), fmaxf(redm[128 + t], redm[192 + t]));
    psum[((size_t)b * 64 + sb) * 64 + t] = ss;
    pmax[((size_t)b * 64 + sb) * 64 + t] = mm;
  }
}

// ---------------------------------------------------------------------------
// final mix + top-16 + one-hot routing (unchanged).
// ---------------------------------------------------------------------------
__global__ void final_topk(const float* __restrict__ psum, const float* __restrict__ pmax,
                           float* __restrict__ out)
{
  __shared__ float fin[4][64];
  const int t = threadIdx.x;
  const int b = t >> 6, n = t & 63;
  float s = 0.f, m = -1e30f;
  for (int j = 0; j < 64; j++) {
    s += psum[((size_t)b * 64 + j) * 64 + n];
    m = fmaxf(m, pmax[((size_t)b * 64 + j) * 64 + n]);
  }
  const float mean = s * (1.0f / 2048.0f);
  fin[b][n] = 0.5f * mean + 0.3f * m + 0.2f * mean;
  __syncthreads();
  if (t < 4) {
    unsigned long long chosen = 0ull;
    for (int j = 0; j < 16; j++) {
      float best = -3e38f; int bi = 0;
      for (int nn = 0; nn < 64; nn++) {
        float v = fin[t][nn];
        if (!((chosen >> nn) & 1ull) && v > best) { best = v; bi = nn; }
      }
      chosen |= 1ull << bi;
      out[t * 16 + j] = (float)bi;
    }
    for (int nn = 0; nn < 64; nn++)
      out[64 + t * 64 + nn] = ((chosen >> nn) & 1ull) ? 1.0f : 0.0f;
  }
}

extern "C" void kernel_launch(void* const* d_in, const int* in_sizes, int n_in,
                              void* d_out, int out_size, void* d_ws, size_t ws_size,
                              hipStream_t stream) {
  const float* x    = (const float*)d_in[0];   // [4,2048,512]
  const float* win  = (const float*)d_in[1];   // [1536,512]
  const float* bin  = (const float*)d_in[2];   // [1536]
  const float* wout = (const float*)d_in[3];   // [512,512]
  const float* bout = (const float*)d_in[4];   // [512]
  const float* cw   = (const float*)d_in[5];   // [64,512]
  const float* cbv  = (const float*)d_in[6];   // [64]
  (void)in_sizes; (void)n_in; (void)ws_size; (void)out_size;

  float* out = (float*)d_out;
  char* ws = (char*)d_ws;
  u16*   qkv_h = (u16*)ws;                                   // 25165824 B (dead after attn)
  u16*   qkv_l = (u16*)(ws + 25165824);                      // 25165824 B (dead after attn)
  float* psum  = (float*)(ws + 67108864);                    //    65536 B
  float* pmax  = (float*)(ws + 67174400);                    //    65536 B
  u16*   winh  = (u16*)(ws + 67239936);                      //  1572864 B
  u16*   winl  = (u16*)(ws + 68812800);                      //  1572864 B
  u16*   wouth = (u16*)(ws + 70385664);                      //   524288 B
  u16*   woutl = (u16*)(ws + 70909952);                      //   524288 B
  float* l0    = (float*)(ws + 71434240);                    //   262144 B
  float* l1    = (float*)(ws + 71696384);                    //   262144 B (end 71958528)
  u16*   xh = (u16*)(ws + 50331648);                         // x planes (gemm1 only)
  u16*   xl = (u16*)(ws + 58720256);
  float* O1 = (float*)(ws + 50331648);                       // overlays dead x planes
  float* attended = out + 320;                               // outputs 0,1 occupy 320
  float* O0 = attended;                                      // consumed before gemm2 writes
  u16*   ctx2_h = qkv_h;                                     // overlays dead qkv_h
  u16*   ctx2_l = qkv_h + 4194304;

  // pre-split f32 inputs into bf16 hi/lo planes
  split_kernel<<<4096, 256, 0, stream>>>(x, xh, xl, 1048576);
  split_kernel<<<768, 256, 0, stream>>>(win, winh, winl, 196608);
  split_kernel<<<256, 256, 0, stream>>>(wout, wouth, woutl, 65536);

  // qkv = x @ W_in^T + b_in   -> hi/lo bf16 planes
  gemm_nt<1><<<dim3(64, 12), 256, 0, stream>>>(
      xh, xl, winh, winl, bin, qkv_h, qkv_l, 8192, 1536, 512);
  // flash attention, KV-split: unnormalized O partials + l partials
  attn_kernel<<<dim3(32, 8, 2), 512, 0, stream>>>(qkv_h, qkv_l, O0, O1, l0, l1);
  // combine partials -> ctx planes (into dead qkv_h region)
  combine_kernel<<<4096, 256, 0, stream>>>(O0, O1, l0, l1, ctx2_h, ctx2_l);
  // attended = ctx @ W_out^T + b_out  -> fp32 straight into d_out
  gemm_nt<0><<<dim3(64, 4), 256, 0, stream>>>(
      ctx2_h, ctx2_l, wouth, woutl, bout, attended, nullptr, 8192, 512, 512);
  // aff + partial sum/max over s
  aff_reduce<<<dim3(4, 64), 256, 0, stream>>>(attended, cw, cbv, psum, pmax);
  // final mix + top-16 + one-hot routing
  final_topk<<<1, 256, 0, stream>>>(psum, pmax, out);
}

// Round 18
// 243.507 us; speedup vs baseline: 1.0500x; 1.0500x over previous
//
#include <hip/hip_runtime.h>
#include <hip/hip_bf16.h>

typedef unsigned short u16;
typedef unsigned int u32;
typedef __bf16 bf16x8 __attribute__((ext_vector_type(8)));
typedef u16 u16x8 __attribute__((ext_vector_type(8)));
typedef u16 u16x4 __attribute__((ext_vector_type(4)));
typedef float f32x4 __attribute__((ext_vector_type(4)));

__device__ __forceinline__ u16 f2bf(float f) {
  union { float f; unsigned u; } v; v.f = f;
  return (u16)((v.u + 0x7FFFu + ((v.u >> 16) & 1u)) >> 16);
}
__device__ __forceinline__ float bf2f(u16 h) {
  union { unsigned u; float f; } v; v.u = ((unsigned)h) << 16;
  return v.f;
}
struct BfPair { u16 hi, lo; };
__device__ __forceinline__ BfPair split2(float f) {
  BfPair r;
  r.hi = f2bf(f);
  r.lo = f2bf(f - bf2f(r.hi));
  return r;
}
__device__ __forceinline__ bf16x8 as_bf16x8(u16x8 u) {
  union { u16x8 u; bf16x8 b; } v; v.u = u; return v.b;
}
// packed f32->bf16 (RNE): low16 = bf16(a), high16 = bf16(b)
__device__ __forceinline__ u32 cvt_pk(float a, float b) {
  u32 r;
  asm volatile("v_cvt_pk_bf16_f32 %0, %1, %2" : "=v"(r) : "v"(a), "v"(b));
  return r;
}

#define MFMA16(a, b, c) __builtin_amdgcn_mfma_f32_16x16x32_bf16((a), (b), (c), 0, 0, 0)

#define GLD16(gp, lp)                                                          \
  __builtin_amdgcn_global_load_lds(                                            \
      (const __attribute__((address_space(1))) void*)(gp),                     \
      (__attribute__((address_space(3))) void*)(lp), 16, 0, 0)

// ---------------------------------------------------------------------------
// Pre-split: f32 -> bf16 hi/lo planes.
// ---------------------------------------------------------------------------
__global__ __launch_bounds__(256) void split_kernel(
    const float* __restrict__ src, u16* __restrict__ hi, u16* __restrict__ lo, int n4)
{
  int i = blockIdx.x * 256 + threadIdx.x;
  if (i >= n4) return;
  f32x4 v = ((const f32x4*)src)[i];
  u16x4 h, l;
  #pragma unroll
  for (int j = 0; j < 4; j++) { BfPair p = split2(v[j]); h[j] = p.hi; l[j] = p.lo; }
  ((u16x4*)hi)[i] = h;
  ((u16x4*)lo)[i] = l;
}

// ---------------------------------------------------------------------------
// NT GEMM, emulated-fp32 via bf16x3, m97 structure (R12 version — measured).
// ---------------------------------------------------------------------------
template<int OUT_PLANES>
__global__ __launch_bounds__(256, 3) void gemm_nt(
    const u16* __restrict__ Ah, const u16* __restrict__ Al,
    const u16* __restrict__ Bh, const u16* __restrict__ Bl,
    const float* __restrict__ bias,
    void* __restrict__ C0, void* __restrict__ C1,
    int M, int N, int K)
{
  __shared__ u16 Ash[128 * 32], Asl[128 * 32];
  __shared__ u16 Bsh[128 * 32], Bsl[128 * 32];
  const int t = threadIdx.x;
  const int lane = t & 63, w = t >> 6;
  const int l15 = lane & 15, g = lane >> 4;
  const int m0 = blockIdx.x * 128, n0 = blockIdx.y * 128;
  const int lrow = lane >> 2;
  const int lchunk = lane & 3;

  f32x4 acc[4][4] = {};

  for (int k0 = 0; k0 < K; k0 += 32) {
    __syncthreads();
    #pragma unroll
    for (int q = 0; q < 2; q++) {
      const int row = w * 32 + q * 16 + lrow;
      const int sw = lchunk ^ (row & 3) ^ ((row >> 2) & 3);
      const size_t ga = (size_t)(m0 + row) * K + k0 + sw * 8;
      const size_t gb = (size_t)(n0 + row) * K + k0 + sw * 8;
      const int ldsbase = (w * 32 + q * 16) * 32;
      GLD16(Ah + ga, &Ash[ldsbase]);
      GLD16(Al + ga, &Asl[ldsbase]);
      GLD16(Bh + gb, &Bsh[ldsbase]);
      GLD16(Bl + gb, &Bsl[ldsbase]);
    }
    __syncthreads();

    bf16x8 bh[4], bl[4];
    #pragma unroll
    for (int n = 0; n < 4; n++) {
      const int row = (w & 1) * 64 + n * 16 + l15;
      const int slot = g ^ (row & 3) ^ ((row >> 2) & 3);
      const int idx = row * 32 + slot * 8;
      bh[n] = *(const bf16x8*)&Bsh[idx];
      bl[n] = *(const bf16x8*)&Bsl[idx];
    }
    #pragma unroll
    for (int m = 0; m < 4; m++) {
      const int row = (w >> 1) * 64 + m * 16 + l15;
      const int slot = g ^ (row & 3) ^ ((row >> 2) & 3);
      const int idx = row * 32 + slot * 8;
      bf16x8 ah = *(const bf16x8*)&Ash[idx];
      bf16x8 al = *(const bf16x8*)&Asl[idx];
      #pragma unroll
      for (int n = 0; n < 4; n++) {
        acc[m][n] = MFMA16(ah, bh[n], acc[m][n]);
        acc[m][n] = MFMA16(ah, bl[n], acc[m][n]);
        acc[m][n] = MFMA16(al, bh[n], acc[m][n]);
      }
    }
  }

  const int r0 = m0 + (w >> 1) * 64;
  const int c0 = n0 + (w & 1) * 64;
  float bs[4];
  #pragma unroll
  for (int n = 0; n < 4; n++) bs[n] = bias[c0 + n * 16 + l15];
  #pragma unroll
  for (int m = 0; m < 4; m++)
    #pragma unroll
    for (int n = 0; n < 4; n++) {
      const int col = c0 + n * 16 + l15;
      #pragma unroll
      for (int r = 0; r < 4; r++) {
        float v = acc[m][n][r] + bs[n];
        size_t idx = (size_t)(r0 + m * 16 + g * 4 + r) * N + col;
        if (OUT_PLANES) {
          BfPair pp = split2(v);
          ((u16*)C0)[idx] = pp.hi;
          ((u16*)C1)[idx] = pp.lo;
        } else {
          ((float*)C0)[idx] = v;
        }
      }
    }
}

// ---------------------------------------------------------------------------
// Flash attention (R15 — verified 102.6 us, absmax 1.2e-4).
// Numerics: Q hi+lo, K hi-only, P hi-only, V hi+lo. This is the empirical
// precision floor: dropping V-lo (R17) flips top-16 indices.
// ---------------------------------------------------------------------------
__global__ __launch_bounds__(512, 2) void attn_kernel(
    const u16* __restrict__ qkv_h, const u16* __restrict__ qkv_l,
    u16* __restrict__ ctx_h, u16* __restrict__ ctx_l)
{
  const int bh = blockIdx.x;              // b*8 + h
  const int b = bh >> 3, h = bh & 7;
  const int q0 = blockIdx.y * 256;
  const int t = threadIdx.x, lane = t & 63, w = t >> 6;
  const int l15 = lane & 15, g = lane >> 4;
  const int wh = w >> 2, wl = w & 3;

  __shared__ u16 Ksh[64 * 72];
  __shared__ u16 Vsh[64 * 72], Vsl[64 * 72];   // V^T, key-swizzled
  __shared__ u16 Ps[8][32 * 72];               // per-wave P (hi only)

  const size_t rowbase = (size_t)b * 2048;
  const float QSC = 0.125f * 1.44269504088896f;  // fold 1/sqrt(64) and log2(e)

  bf16x8 qbh[2][2], qbl[2][2];
  #pragma unroll
  for (int i = 0; i < 2; i++) {
    size_t qoff = (rowbase + q0 + wh * 128 + i * 64 + wl * 16 + l15) * 1536 + h * 64 + g * 8;
    #pragma unroll
    for (int kc = 0; kc < 2; kc++) {
      u16x8 uh = *(const u16x8*)(qkv_h + qoff + kc * 32);
      u16x8 ul = *(const u16x8*)(qkv_l + qoff + kc * 32);
      #pragma unroll
      for (int j = 0; j < 8; j++) {
        float v = (bf2f(uh[j]) + bf2f(ul[j])) * QSC;
        BfPair p = split2(v);
        uh[j] = p.hi; ul[j] = p.lo;
      }
      qbh[i][kc] = as_bf16x8(uh);
      qbl[i][kc] = as_bf16x8(ul);
    }
  }

  f32x4 oacc[2][4] = {};
  float l_q[2] = {0.f, 0.f};

  const int srow = t >> 3, scol = (t & 7) * 8;
  u16x8 skh, svh, svl;
  {
    size_t off = (rowbase + srow) * 1536 + h * 64 + scol;   // kt = 0
    skh = *(const u16x8*)(qkv_h + off + 512);
    svh = *(const u16x8*)(qkv_h + off + 1024);
    svl = *(const u16x8*)(qkv_l + off + 1024);
  }

  for (int kt = 0; kt < 32; kt++) {
    __syncthreads();
    {
      *(u16x8*)&Ksh[srow * 72 + scol] = skh;
      int rk = (srow + scol) & 63;               // key-swizzle
      #pragma unroll
      for (int j = 0; j < 8; j++) {
        Vsh[(scol + j) * 72 + rk] = svh[j];
        Vsl[(scol + j) * 72 + rk] = svl[j];
      }
    }
    if (kt + 1 < 32) {
      size_t off = (rowbase + (kt + 1) * 64 + srow) * 1536 + h * 64 + scol;
      skh = *(const u16x8*)(qkv_h + off + 512);
      svh = *(const u16x8*)(qkv_h + off + 1024);
      svl = *(const u16x8*)(qkv_l + off + 1024);
    }
    __syncthreads();

    f32x4 sa0[4] = {}, sa1[4] = {};
    #pragma unroll
    for (int kc = 0; kc < 2; kc++) {
      #pragma unroll
      for (int cb = 0; cb < 4; cb++) {
        int ki = (cb * 16 + l15) * 72 + g * 8 + kc * 32;
        bf16x8 kh = *(const bf16x8*)&Ksh[ki];
        sa0[cb] = MFMA16(kh, qbh[0][kc], sa0[cb]);
        sa1[cb] = MFMA16(kh, qbh[1][kc], sa1[cb]);
        sa0[cb] = MFMA16(kh, qbl[0][kc], sa0[cb]);
        sa1[cb] = MFMA16(kh, qbl[1][kc], sa1[cb]);
      }
    }

    // fixed-max softmax: p = exp2(s'); pack hi words only
    u32 hw[2][4][2];
    #pragma unroll
    for (int i = 0; i < 2; i++) {
      f32x4* sa = (i == 0) ? sa0 : sa1;
      float rs = 0.f;
      #pragma unroll
      for (int cb = 0; cb < 4; cb++) {
        #pragma unroll
        for (int r = 0; r < 4; r++) {
          float p = exp2f(sa[cb][r]);
          sa[cb][r] = p;
          rs += p;
        }
        hw[i][cb][0] = cvt_pk(sa[cb][0], sa[cb][1]);
        hw[i][cb][1] = cvt_pk(sa[cb][2], sa[cb][3]);
      }
      rs += __shfl_xor(rs, 16, 64);
      rs += __shfl_xor(rs, 32, 64);
      l_q[i] += rs;
    }

    // P hi plane: write, read A-frags (single roundtrip)
    #pragma unroll
    for (int i = 0; i < 2; i++)
      #pragma unroll
      for (int cb = 0; cb < 4; cb++) {
        u32* dst = (u32*)&Ps[w][(i * 16 + l15) * 72 + cb * 16 + g * 4];
        dst[0] = hw[i][cb][0]; dst[1] = hw[i][cb][1];
      }
    asm volatile("s_waitcnt lgkmcnt(0)" ::: "memory");
    __builtin_amdgcn_sched_barrier(0);
    bf16x8 pah[2][2];
    #pragma unroll
    for (int i = 0; i < 2; i++)
      #pragma unroll
      for (int kc = 0; kc < 2; kc++)
        pah[i][kc] = *(const bf16x8*)&Ps[w][(i * 16 + l15) * 72 + kc * 32 + g * 8];

    // PV for both tiles: pah * (vbh + vbl)
    #pragma unroll
    for (int kc = 0; kc < 2; kc++) {
      #pragma unroll
      for (int cb = 0; cb < 4; cb++) {
        int d = cb * 16 + l15;
        int rk0 = (g * 8 + kc * 32 + (d & 56)) & 63;
        bf16x8 vbh = *(const bf16x8*)&Vsh[d * 72 + rk0];
        bf16x8 vbl = *(const bf16x8*)&Vsl[d * 72 + rk0];
        oacc[0][cb] = MFMA16(pah[0][kc], vbh, oacc[0][cb]);
        oacc[1][cb] = MFMA16(pah[1][kc], vbh, oacc[1][cb]);
        oacc[0][cb] = MFMA16(pah[0][kc], vbl, oacc[0][cb]);
        oacc[1][cb] = MFMA16(pah[1][kc], vbl, oacc[1][cb]);
      }
    }
  }

  #pragma unroll
  for (int i = 0; i < 2; i++)
    #pragma unroll
    for (int r = 0; r < 4; r++) {
      float lq = __shfl(l_q[i], g * 4 + r, 64);
      float inv = 1.0f / lq;
      int row = q0 + wh * 128 + i * 64 + wl * 16 + g * 4 + r;
      size_t base = (rowbase + row) * 512 + h * 64;
      #pragma unroll
      for (int cb = 0; cb < 4; cb++) {
        BfPair pp = split2(oacc[i][cb][r] * inv);
        ctx_h[base + cb * 16 + l15] = pp.hi;
        ctx_l[base + cb * 16 + l15] = pp.lo;
      }
    }
}

// ---------------------------------------------------------------------------
// aff + per-32-row partial sum/max over s (unchanged, measured fast).
// ---------------------------------------------------------------------------
__global__ __launch_bounds__(256) void aff_reduce(
    const float* __restrict__ att, const float* __restrict__ cw,
    const float* __restrict__ cbias, float* __restrict__ psum, float* __restrict__ pmax)
{
  const int b = blockIdx.x, sb = blockIdx.y;
  const int t = threadIdx.x;
  const int n = t & 63, rg = t >> 6;
  __shared__ float cws[64 * 65];
  __shared__ float ats[32 * 65];
  __shared__ float reds[256], redm[256];

  float acc[8] = {};
  for (int kc = 0; kc < 8; kc++) {
    __syncthreads();
    #pragma unroll
    for (int i = 0; i < 4; i++) {
      int c = t + i * 256;
      int row = c >> 4, col = (c & 15) * 4;
      f32x4 v = *(const f32x4*)(cw + (size_t)row * 512 + kc * 64 + col);
      cws[row * 65 + col + 0] = v[0]; cws[row * 65 + col + 1] = v[1];
      cws[row * 65 + col + 2] = v[2]; cws[row * 65 + col + 3] = v[3];
    }
    #pragma unroll
    for (int i = 0; i < 2; i++) {
      int c = t + i * 256;
      int row = c >> 4, col = (c & 15) * 4;
      f32x4 v = *(const f32x4*)(att + ((size_t)b * 2048 + sb * 32 + row) * 512 + kc * 64 + col);
      ats[row * 65 + col + 0] = v[0]; ats[row * 65 + col + 1] = v[1];
      ats[row * 65 + col + 2] = v[2]; ats[row * 65 + col + 3] = v[3];
    }
    __syncthreads();
    for (int k = 0; k < 64; k++) {
      float c = cws[n * 65 + k];
      #pragma unroll
      for (int r = 0; r < 8; r++)
        acc[r] += ats[(rg * 8 + r) * 65 + k] * c;
    }
  }
  const float bn = cbias[n];
  float s = 0.f, m = -1e30f;
  #pragma unroll
  for (int r = 0; r < 8; r++) {
    float v = acc[r] + bn;
    s += v; m = fmaxf(m, v);
  }
  reds[t] = s; redm[t] = m;
  __syncthreads();
  if (t < 64) {
    float ss = reds[t] + reds[64 + t] + reds[128 + t] + reds[192 + t];
    float mm = fmaxf(fmaxf(redm[t], redm[64 + t]), fmaxf(redm[128 + t], redm[192 + t]));
    psum[((size_t)b * 64 + sb) * 64 + t] = ss;
    pmax[((size_t)b * 64 + sb) * 64 + t] = mm;
  }
}

// ---------------------------------------------------------------------------
// final mix + top-16 + one-hot routing (unchanged).
// ---------------------------------------------------------------------------
__global__ void final_topk(const float* __restrict__ psum, const float* __restrict__ pmax,
                           float* __restrict__ out)
{
  __shared__ float fin[4][64];
  const int t = threadIdx.x;
  const int b = t >> 6, n = t & 63;
  float s = 0.f, m = -1e30f;
  for (int j = 0; j < 64; j++) {
    s += psum[((size_t)b * 64 + j) * 64 + n];
    m = fmaxf(m, pmax[((size_t)b * 64 + j) * 64 + n]);
  }
  const float mean = s * (1.0f / 2048.0f);
  fin[b][n] = 0.5f * mean + 0.3f * m + 0.2f * mean;
  __syncthreads();
  if (t < 4) {
    unsigned long long chosen = 0ull;
    for (int j = 0; j < 16; j++) {
      float best = -3e38f; int bi = 0;
      for (int nn = 0; nn < 64; nn++) {
        float v = fin[t][nn];
        if (!((chosen >> nn) & 1ull) && v > best) { best = v; bi = nn; }
      }
      chosen |= 1ull << bi;
      out[t * 16 + j] = (float)bi;
    }
    for (int nn = 0; nn < 64; nn++)
      out[64 + t * 64 + nn] = ((chosen >> nn) & 1ull) ? 1.0f : 0.0f;
  }
}

extern "C" void kernel_launch(void* const* d_in, const int* in_sizes, int n_in,
                              void* d_out, int out_size, void* d_ws, size_t ws_size,
                              hipStream_t stream) {
  const float* x    = (const float*)d_in[0];   // [4,2048,512]
  const float* win  = (const float*)d_in[1];   // [1536,512]
  const float* bin  = (const float*)d_in[2];   // [1536]
  const float* wout = (const float*)d_in[3];   // [512,512]
  const float* bout = (const float*)d_in[4];   // [512]
  const float* cw   = (const float*)d_in[5];   // [64,512]
  const float* cbv  = (const float*)d_in[6];   // [64]
  (void)in_sizes; (void)n_in; (void)ws_size; (void)out_size;

  float* out = (float*)d_out;
  char* ws = (char*)d_ws;
  u16*   qkv_h = (u16*)ws;                                   // 25165824 B
  u16*   qkv_l = (u16*)(ws + 25165824);                      // 25165824 B
  u16*   ctx_h = (u16*)(ws + 50331648);                      //  8388608 B (aliases xh)
  u16*   ctx_l = (u16*)(ws + 58720256);                      //  8388608 B (aliases xl)
  float* psum  = (float*)(ws + 67108864);                    //    65536 B
  float* pmax  = (float*)(ws + 67174400);                    //    65536 B
  u16*   winh  = (u16*)(ws + 67239936);                      //  1572864 B
  u16*   winl  = (u16*)(ws + 68812800);                      //  1572864 B
  u16*   wouth = (u16*)(ws + 70385664);                      //   524288 B
  u16*   woutl = (u16*)(ws + 70909952);                      //   524288 B
  u16*   xh = ctx_h, *xl = ctx_l;                            // x planes, dead after gemm1
  float* attended = out + 320;                               // outputs 0,1 occupy 320

  // pre-split f32 inputs into bf16 hi/lo planes
  split_kernel<<<4096, 256, 0, stream>>>(x, xh, xl, 1048576);
  split_kernel<<<768, 256, 0, stream>>>(win, winh, winl, 196608);
  split_kernel<<<256, 256, 0, stream>>>(wout, wouth, woutl, 65536);

  // qkv = x @ W_in^T + b_in   -> hi/lo bf16 planes
  gemm_nt<1><<<dim3(64, 12), 256, 0, stream>>>(
      xh, xl, winh, winl, bin, qkv_h, qkv_l, 8192, 1536, 512);
  // flash attention -> ctx hi/lo planes (overwrites x planes)
  attn_kernel<<<dim3(32, 8), 512, 0, stream>>>(qkv_h, qkv_l, ctx_h, ctx_l);
  // attended = ctx @ W_out^T + b_out  -> fp32 straight into d_out
  gemm_nt<0><<<dim3(64, 4), 256, 0, stream>>>(
      ctx_h, ctx_l, wouth, woutl, bout, attended, nullptr, 8192, 512, 512);
  // aff + partial sum/max over s
  aff_reduce<<<dim3(4, 64), 256, 0, stream>>>(attended, cw, cbv, psum, pmax);
  // final mix + top-16 + one-hot routing
  final_topk<<<1, 256, 0, stream>>>(psum, pmax, out);
}